// Round 4
// baseline (474.886 us; speedup 1.0000x reference)
//
#include <hip/hip_runtime.h>

#define H 512
#define OW 128
#define NB 16384

typedef float f32x4 __attribute__((ext_vector_type(4)));
typedef short short8 __attribute__((ext_vector_type(8)));
typedef unsigned short ushort8v __attribute__((ext_vector_type(8)));

static __device__ __forceinline__ unsigned short f2bf(float f) {
    union { float f; unsigned u; } v; v.f = f;
    return (unsigned short)((v.u + 0x7FFFu + ((v.u >> 16) & 1u)) >> 16);  // RNE
}

static __device__ __forceinline__ f32x4 mfma16(short8 a, short8 b, f32x4 c) {
    return __builtin_amdgcn_mfma_f32_16x16x32_bf16(a, b, c, 0, 0, 0);
}

// Swizzled LDS tile [rows][64 shorts]: 16B chunk ch of row r lives at phys
// chunk ch^(r&7). Verified conflict-free (round 2/3: SQ_LDS_BANK_CONFLICT = 0).
static __device__ __forceinline__ void sw_write(unsigned short* l, int row, int ch, ushort8v v) {
    *(ushort8v*)&l[row * 64 + ((ch ^ (row & 7)) << 3)] = v;
}
static __device__ __forceinline__ short8 sw_read(const unsigned short* l, int row, int ch) {
    return *(const short8*)&l[row * 64 + ((ch ^ (row & 7)) << 3)];
}

// ---- prep: weights transpose+cast, x cast (unchanged, proven) ----
__global__ void prep_w1(const float* __restrict__ share_W1,
                        const float* __restrict__ task_W1,
                        unsigned short* __restrict__ w1t) {
    const int inst = blockIdx.z;
    const float* src = (inst < 5) ? (share_W1 + (size_t)inst * H * H)
                                  : (task_W1 + (size_t)(inst - 5) * H * H);
    unsigned short* dst = w1t + (size_t)inst * H * H;
    const int g = blockIdx.x * 256 + threadIdx.x;
    const int n = g & (H - 1);
    const int kc = g >> 9;
    float v[8];
#pragma unroll
    for (int i = 0; i < 8; ++i) v[i] = src[(size_t)(kc * 8 + i) * H + n];
    ushort8v o;
#pragma unroll
    for (int i = 0; i < 8; ++i) o[i] = f2bf(v[i]);
    *(ushort8v*)&dst[(size_t)n * H + kc * 8] = o;
}

__global__ void prep_w2(const float* __restrict__ share_W2,
                        const float* __restrict__ task_W2,
                        unsigned short* __restrict__ w2t) {
    const int inst = blockIdx.z;
    const float* src = (inst < 5) ? (share_W2 + (size_t)inst * H * OW)
                                  : (task_W2 + (size_t)(inst - 5) * H * OW);
    unsigned short* dst = w2t + (size_t)inst * OW * H;
    const int g = blockIdx.x * 256 + threadIdx.x;
    const int n = g & (OW - 1);
    const int kc = g >> 7;
    float v[8];
#pragma unroll
    for (int i = 0; i < 8; ++i) v[i] = src[(size_t)(kc * 8 + i) * OW + n];
    ushort8v o;
#pragma unroll
    for (int i = 0; i < 8; ++i) o[i] = f2bf(v[i]);
    *(ushort8v*)&dst[(size_t)n * H + kc * 8] = o;
}

__global__ void prep_x(const float* __restrict__ x0, const float* __restrict__ x1,
                       const float* __restrict__ x2, unsigned short* __restrict__ xb) {
    const int z = blockIdx.z;
    const float* s = (z == 0) ? x0 : (z == 1 ? x1 : x2);
    const size_t g = (size_t)(blockIdx.x * 256 + threadIdx.x) * 8;
    float4 a = *(const float4*)&s[g];
    float4 b = *(const float4*)&s[g + 4];
    ushort8v o;
    o[0] = f2bf(a.x); o[1] = f2bf(a.y); o[2] = f2bf(a.z); o[3] = f2bf(a.w);
    o[4] = f2bf(b.x); o[5] = f2bf(b.y); o[6] = f2bf(b.z); o[7] = f2bf(b.w);
    *(ushort8v*)&xb[(size_t)z * NB * H + g] = o;
}

// ---- GEMM1: h = relu(x @ W1 + b1), bf16 out to hbuf ----
// grid (2560, nz): bid.x = e + 5*(nt + 4*rowtile), z = z0 + bid.y.
// hbuf bank offset = bid.y * hstride (hstride=0 in fallback per-z mode).
__global__ __launch_bounds__(256, 3) void gemm1(
    const unsigned short* __restrict__ xb, const unsigned short* __restrict__ w1t,
    const float* __restrict__ share_b1, const float* __restrict__ task_b1,
    unsigned short* __restrict__ hbuf, int z0, long long hstride)
{
    __shared__ unsigned short smem[128 * 136];   // staging 2x8192; repack 128x136
    unsigned short* sA  = smem;                  // [128][64]
    unsigned short* sBt = smem + 8192;           // [128][64]
    unsigned short* sH  = smem;                  // [128][136] repack (alias)

    const int tid = threadIdx.x;
    const int lane = tid & 63;
    const int wave = tid >> 6;
    const int wy = wave >> 1, wx = wave & 1;
    const int lm = lane & 15, lq = lane >> 4;
    const int r8 = tid >> 3, ch = tid & 7;

    const int bid = blockIdx.x;
    const int e = bid % 5;
    const int nt = (bid / 5) & 3;
    const int rowtile = bid / 20;
    const int z = z0 + blockIdx.y;
    const int inst = z * 5 + e;

    const unsigned short* xp = xb + ((size_t)z * NB + rowtile * 128) * H;
    const unsigned short* wp = w1t + (size_t)inst * H * H + (size_t)(nt * 128) * H;
    const float* b1 = (z == 0) ? (share_b1 + e * H) : (task_b1 + ((z - 1) * 5 + e) * H);
    unsigned short* hp = hbuf + (size_t)blockIdx.y * hstride
                       + ((size_t)e * NB + rowtile * 128) * H + nt * 128;

    ushort8v rA[4], rB[4];
#pragma unroll
    for (int it = 0; it < 4; ++it) {
        rA[it] = *(const ushort8v*)&xp[(size_t)(it * 32 + r8) * H + ch * 8];
        rB[it] = *(const ushort8v*)&wp[(size_t)(it * 32 + r8) * H + ch * 8];
    }

    const f32x4 z4 = {0.f, 0.f, 0.f, 0.f};
    f32x4 acc[4][4];
#pragma unroll
    for (int i = 0; i < 4; ++i)
#pragma unroll
        for (int j = 0; j < 4; ++j) acc[i][j] = z4;

    for (int kt = 0; kt < 8; ++kt) {
        __syncthreads();
#pragma unroll
        for (int it = 0; it < 4; ++it) sw_write(sA, it * 32 + r8, ch, rA[it]);
#pragma unroll
        for (int it = 0; it < 4; ++it) sw_write(sBt, it * 32 + r8, ch, rB[it]);
        __syncthreads();
        if (kt < 7) {
            const int k0 = (kt + 1) * 64;
#pragma unroll
            for (int it = 0; it < 4; ++it) {
                rA[it] = *(const ushort8v*)&xp[(size_t)(it * 32 + r8) * H + k0 + ch * 8];
                rB[it] = *(const ushort8v*)&wp[(size_t)(it * 32 + r8) * H + k0 + ch * 8];
            }
        }
#pragma unroll
        for (int kk = 0; kk < 2; ++kk) {
            short8 af[4], bf[4];
#pragma unroll
            for (int i = 0; i < 4; ++i) af[i] = sw_read(sA, wy * 64 + i * 16 + lm, kk * 4 + lq);
#pragma unroll
            for (int j = 0; j < 4; ++j) bf[j] = sw_read(sBt, wx * 64 + j * 16 + lm, kk * 4 + lq);
#pragma unroll
            for (int i = 0; i < 4; ++i)
#pragma unroll
                for (int j = 0; j < 4; ++j) acc[i][j] = mfma16(af[i], bf[j], acc[i][j]);
        }
    }

    // epilogue: +b1, relu, bf16 -> sH repack -> coalesced b128 store
    __syncthreads();
#pragma unroll
    for (int j = 0; j < 4; ++j) {
        const int col = wx * 64 + j * 16 + lm;
        const float b1v = b1[nt * 128 + col];
#pragma unroll
        for (int i = 0; i < 4; ++i)
#pragma unroll
            for (int r = 0; r < 4; ++r) {
                const int row = wy * 64 + i * 16 + lq * 4 + r;
                sH[row * 136 + col] = f2bf(fmaxf(acc[i][j][r] + b1v, 0.f));
            }
    }
    __syncthreads();
    {
        const int rr = tid >> 4, cc = tid & 15;
#pragma unroll
        for (int it = 0; it < 8; ++it) {
            const int row = rr + it * 16;
            ushort8v v = *(const ushort8v*)&sH[row * 136 + cc * 8];
            *(ushort8v*)&hp[(size_t)row * H + cc * 8] = v;
        }
    }
}

// ---- GEMM2: out = h @ W2 + b2, fp32. grid (1280, nz): bid.x = e + 5*rt ----
__global__ __launch_bounds__(256, 4) void gemm2(
    const unsigned short* __restrict__ hbuf, const unsigned short* __restrict__ w2t,
    const float* __restrict__ share_b2, const float* __restrict__ task_b2,
    float* __restrict__ out, int z0, long long hstride)
{
    __shared__ unsigned short smem[4096 + 8192];   // sH 64x64, sW2 128x64 = 24 KB
    unsigned short* sH  = smem;
    unsigned short* sW2 = smem + 4096;

    const int tid = threadIdx.x;
    const int lane = tid & 63;
    const int wave = tid >> 6;
    const int wy = wave >> 1, wx = wave & 1;
    const int lm = lane & 15, lq = lane >> 4;
    const int r8 = tid >> 3, ch = tid & 7;

    const int bid = blockIdx.x;
    const int e = bid % 5;
    const int rt = bid / 5;                       // 0..255
    const int z = z0 + blockIdx.y;
    const int inst = z * 5 + e;

    const unsigned short* hp = hbuf + (size_t)blockIdx.y * hstride
                             + ((size_t)e * NB + rt * 64) * H;
    const unsigned short* wp = w2t + (size_t)inst * OW * H;
    const float* b2 = (z == 0) ? (share_b2 + e * OW) : (task_b2 + ((z - 1) * 5 + e) * OW);
    float* op = out + ((size_t)inst * NB + rt * 64) * OW;

    ushort8v rH[2], rW[4];
#pragma unroll
    for (int it = 0; it < 2; ++it)
        rH[it] = *(const ushort8v*)&hp[(size_t)(it * 32 + r8) * H + ch * 8];
#pragma unroll
    for (int it = 0; it < 4; ++it)
        rW[it] = *(const ushort8v*)&wp[(size_t)(it * 32 + r8) * H + ch * 8];

    const f32x4 z4 = {0.f, 0.f, 0.f, 0.f};
    f32x4 acc[2][4];
#pragma unroll
    for (int i = 0; i < 2; ++i)
#pragma unroll
        for (int j = 0; j < 4; ++j) acc[i][j] = z4;

    for (int kt = 0; kt < 8; ++kt) {
        __syncthreads();
#pragma unroll
        for (int it = 0; it < 2; ++it) sw_write(sH, it * 32 + r8, ch, rH[it]);
#pragma unroll
        for (int it = 0; it < 4; ++it) sw_write(sW2, it * 32 + r8, ch, rW[it]);
        __syncthreads();
        if (kt < 7) {
            const int k0 = (kt + 1) * 64;
#pragma unroll
            for (int it = 0; it < 2; ++it)
                rH[it] = *(const ushort8v*)&hp[(size_t)(it * 32 + r8) * H + k0 + ch * 8];
#pragma unroll
            for (int it = 0; it < 4; ++it)
                rW[it] = *(const ushort8v*)&wp[(size_t)(it * 32 + r8) * H + k0 + ch * 8];
        }
#pragma unroll
        for (int kk = 0; kk < 2; ++kk) {
            short8 af[2], bf[4];
#pragma unroll
            for (int i = 0; i < 2; ++i) af[i] = sw_read(sH, wy * 32 + i * 16 + lm, kk * 4 + lq);
#pragma unroll
            for (int j = 0; j < 4; ++j) bf[j] = sw_read(sW2, wx * 64 + j * 16 + lm, kk * 4 + lq);
#pragma unroll
            for (int i = 0; i < 2; ++i)
#pragma unroll
                for (int j = 0; j < 4; ++j) acc[i][j] = mfma16(af[i], bf[j], acc[i][j]);
        }
    }

#pragma unroll
    for (int j = 0; j < 4; ++j) {
        const int col = wx * 64 + j * 16 + lm;
        const float b2v = b2[col];
#pragma unroll
        for (int i = 0; i < 2; ++i)
#pragma unroll
            for (int r = 0; r < 4; ++r) {
                const int row = wy * 32 + i * 16 + lq * 4 + r;
                op[(size_t)row * OW + col] = acc[i][j][r] + b2v;
            }
    }
}

extern "C" void kernel_launch(void* const* d_in, const int* in_sizes, int n_in,
                              void* d_out, int out_size, void* d_ws, size_t ws_size,
                              hipStream_t stream) {
    const float* share_x  = (const float*)d_in[0];
    const float* task_x0  = (const float*)d_in[1];
    const float* task_x1  = (const float*)d_in[2];
    const float* share_W1 = (const float*)d_in[3];
    const float* share_b1 = (const float*)d_in[4];
    const float* share_W2 = (const float*)d_in[5];
    const float* share_b2 = (const float*)d_in[6];
    const float* task_W1  = (const float*)d_in[7];
    const float* task_b1  = (const float*)d_in[8];
    const float* task_W2  = (const float*)d_in[9];
    const float* task_b2  = (const float*)d_in[10];
    float* out = (float*)d_out;

    // ws layout: w1t 7.86M | w2t 1.97M | xb 50.3M | hbuf (1 or 3 banks x 83.9M)
    unsigned short* w1t  = (unsigned short*)d_ws;
    unsigned short* w2t  = w1t + (size_t)15 * H * H;
    unsigned short* xb   = w2t + (size_t)15 * OW * H;
    unsigned short* hbuf = xb + (size_t)3 * NB * H;

    const size_t base_elems = (size_t)15 * H * H + (size_t)15 * OW * H + (size_t)3 * NB * H;
    const size_t hbuf_one   = (size_t)5 * NB * H;                 // elems per bank
    const bool   big = ws_size >= (base_elems + 3 * hbuf_one) * sizeof(unsigned short);

    prep_w1<<<dim3(128, 1, 15), 256, 0, stream>>>(share_W1, task_W1, w1t);
    prep_w2<<<dim3(32, 1, 15), 256, 0, stream>>>(share_W2, task_W2, w2t);
    prep_x <<<dim3(4096, 1, 3), 256, 0, stream>>>(share_x, task_x0, task_x1, xb);

    if (big) {
        // single launches, z in blockIdx.y: zero tail on gemm1 (7680 = 10 full
        // occupancy-waves at 3 blk/CU), ~6% tail on gemm2 (3840 @ 4 blk/CU)
        gemm1<<<dim3(2560, 3), 256, 0, stream>>>(xb, w1t, share_b1, task_b1,
                                                 hbuf, 0, (long long)hbuf_one);
        gemm2<<<dim3(1280, 3), 256, 0, stream>>>(hbuf, w2t, share_b2, task_b2,
                                                 out, 0, (long long)hbuf_one);
    } else {
        for (int z = 0; z < 3; ++z) {
            gemm1<<<dim3(2560, 1), 256, 0, stream>>>(xb, w1t, share_b1, task_b1,
                                                     hbuf, z, 0);
            gemm2<<<dim3(1280, 1), 256, 0, stream>>>(hbuf, w2t, share_b2, task_b2,
                                                     out, z, 0);
        }
    }
}